// Round 6
// baseline (1299.053 us; speedup 1.0000x reference)
//
#include <hip/hip_runtime.h>
#include <stdint.h>
#include <stddef.h>
#include <vector>
#include <algorithm>
#include <utility>

// Problem constants (B=2, L=4096, D=256, H=8, K=sqrt(L)=64, 10 Lloyd iters)
#define NPTS 8192
#define DIM  256
#define KC   64
#define LSEQ 4096
#define NB   2
#define KM_ITERS 10
#define NCHUNK 64     // 8192/128 points per summation chunk (bit-exact structure)
#define NBLK 64       // persistent kmeans blocks (block = chunk = cluster)
#define XPITCH 260    // padded LDS row for X tile (breaks bank aliasing)

// JAX threefry mode: 1 = partitionable (default since jax 0.4.36), 0 = original
#define JAX_THREEFRY_PARTITIONABLE 1

// ---------------- static device scratch (fully rewritten every call) --------
__device__ float g_R[NPTS * DIM];          // 8 MB   rotated points (read-only in kmeans, L2-cached)
__device__ float g_xsq[NPTS];              // 32 KB  per-point squared norm (read-only in kmeans)
__device__ float g_centT[DIM * KC];        // 64 KB  centroids transposed [d][k]  (SC1 coherent)
__device__ float g_csq[KC];                // per-centroid squared norm           (SC1 coherent)
__device__ int   g_idx[NPTS];              // final assignments (= cid)
__device__ float g_part[NCHUNK][KC][DIM];  // 4 MB   chunked segment sums         (SC1 coherent)
__device__ int   g_pcnt[NCHUNK][KC];       // chunked counts                      (SC1 coherent)

// Monotone ticket grid barrier state (persists across replays; never reset —
// tickets/releases only grow, so behavior is identical every launch).
__device__ unsigned g_ticket  = 0;
__device__ unsigned g_release = 0;

// ---- L3-coherent (cross-XCD) scalar access: relaxed agent-scope atomics ----
// These compile to SC1-flagged global ops that are serviced at the device
// coherence point, bypassing the non-coherent per-XCD L2s. No fences needed.
__device__ __forceinline__ float coh_ld(const float* p) {
  return __hip_atomic_load(p, __ATOMIC_RELAXED, __HIP_MEMORY_SCOPE_AGENT);
}
__device__ __forceinline__ int coh_ldi(const int* p) {
  return __hip_atomic_load(p, __ATOMIC_RELAXED, __HIP_MEMORY_SCOPE_AGENT);
}
__device__ __forceinline__ void coh_st(float* p, float v) {
  __hip_atomic_store(p, v, __ATOMIC_RELAXED, __HIP_MEMORY_SCOPE_AGENT);
}
__device__ __forceinline__ void coh_sti(int* p, int v) {
  __hip_atomic_store(p, v, __ATOMIC_RELAXED, __HIP_MEMORY_SCOPE_AGENT);
}

// Cheap grid barrier: no __threadfence (no L2 writeback/invalidate).
// s_waitcnt vmcnt(0) guarantees this block's prior SC1 stores have reached the
// coherence point before the ticket increment becomes visible.
__device__ __forceinline__ void grid_barrier() {
  __syncthreads();
  if (threadIdx.x == 0) {
    asm volatile("s_waitcnt vmcnt(0) lgkmcnt(0)" ::: "memory");
    const unsigned my = __hip_atomic_fetch_add(&g_ticket, 1u, __ATOMIC_RELAXED,
                                               __HIP_MEMORY_SCOPE_AGENT);
    const unsigned target = (my / NBLK + 1u) * NBLK;
    if (my % NBLK == NBLK - 1u) {
      __hip_atomic_store(&g_release, target, __ATOMIC_RELAXED,
                         __HIP_MEMORY_SCOPE_AGENT);
    } else {
      while (__hip_atomic_load(&g_release, __ATOMIC_RELAXED,
                               __HIP_MEMORY_SCOPE_AGENT) < target) {
        __builtin_amdgcn_s_sleep(8);
      }
    }
    asm volatile("" ::: "memory");  // compiler barrier: no hoisting across poll
  }
  __syncthreads();
}

// ---------------- host threefry2x32 (exact JAX semantics) -------------------
static inline uint32_t rotl32(uint32_t x, int r) { return (x << r) | (x >> (32 - r)); }

static void threefry2x32(uint32_t k0, uint32_t k1, uint32_t x0, uint32_t x1,
                         uint32_t& o0, uint32_t& o1) {
  const uint32_t ks0 = k0, ks1 = k1, ks2 = k0 ^ k1 ^ 0x1BD11BDAu;
  const int r1[4] = {13, 15, 26, 6}, r2[4] = {17, 29, 16, 24};
  x0 += ks0; x1 += ks1;
  for (int i = 0; i < 4; ++i) { x0 += x1; x1 = rotl32(x1, r1[i]); x1 ^= x0; }
  x0 += ks1; x1 += ks2 + 1u;
  for (int i = 0; i < 4; ++i) { x0 += x1; x1 = rotl32(x1, r2[i]); x1 ^= x0; }
  x0 += ks2; x1 += ks0 + 2u;
  for (int i = 0; i < 4; ++i) { x0 += x1; x1 = rotl32(x1, r1[i]); x1 ^= x0; }
  x0 += ks0; x1 += ks1 + 3u;
  for (int i = 0; i < 4; ++i) { x0 += x1; x1 = rotl32(x1, r2[i]); x1 ^= x0; }
  x0 += ks1; x1 += ks2 + 4u;
  for (int i = 0; i < 4; ++i) { x0 += x1; x1 = rotl32(x1, r1[i]); x1 ^= x0; }
  x0 += ks2; x1 += ks0 + 5u;
  o0 = x0; o1 = x1;
}

struct InitIdx { int v[KC]; };

// jax.random.choice(key(42), 8192, (64,), replace=False)
//  = permutation(key, arange(8192))[:64]  (2-round threefry shuffle)
static InitIdx compute_init_indices() {
  uint32_t k0 = 0u, k1 = 42u;  // jax.random.key(42) -> [0, 42]
  std::vector<int> val(NPTS);
  for (int i = 0; i < NPTS; ++i) val[i] = i;
  std::vector<std::pair<uint32_t, int>> kv(NPTS);
  for (int round = 0; round < 2; ++round) {
    uint32_t nk0, nk1, sk0, sk1;
#if JAX_THREEFRY_PARTITIONABLE
    threefry2x32(k0, k1, 0u, 0u, nk0, nk1);
    threefry2x32(k0, k1, 0u, 1u, sk0, sk1);
    k0 = nk0; k1 = nk1;
    for (int i = 0; i < NPTS; ++i) {
      uint32_t o0, o1;
      threefry2x32(sk0, sk1, 0u, (uint32_t)i, o0, o1);
      kv[i] = std::make_pair(o0 ^ o1, val[i]);
    }
#else
    uint32_t a0, a1, b0, b1;
    threefry2x32(k0, k1, 0u, 2u, a0, a1);
    threefry2x32(k0, k1, 1u, 3u, b0, b1);
    nk0 = a0; nk1 = b0; sk0 = a1; sk1 = b1;
    k0 = nk0; k1 = nk1;
    for (int i = 0; i < NPTS / 2; ++i) {
      uint32_t o0, o1;
      threefry2x32(sk0, sk1, (uint32_t)i, (uint32_t)(i + NPTS / 2), o0, o1);
      kv[i] = std::make_pair(o0, 0);
      kv[i + NPTS / 2] = std::make_pair(o1, 0);
    }
    for (int i = 0; i < NPTS; ++i) kv[i].second = val[i];
#endif
    std::stable_sort(kv.begin(), kv.end(),
                     [](const std::pair<uint32_t, int>& a,
                        const std::pair<uint32_t, int>& b) { return a.first < b.first; });
    for (int i = 0; i < NPTS; ++i) val[i] = kv[i].second;
  }
  InitIdx ii;
  for (int k = 0; k < KC; ++k) ii.v[k] = val[k];
  return ii;
}

// ---------------- kernels ---------------------------------------------------

// Fused R-GEMM + xsq. R[b,l,e] = sum_d qk[b,l,d]*W[b,d,e]; 8 rows per block.
// xsq: per-lane float4 square-sum over dims 4t..4t+3, then 64-lane butterfly.
__global__ void __launch_bounds__(256) k_R_xsq(const float* __restrict__ qk,
                                               const float* __restrict__ W) {
  __shared__ float q[8][DIM];
  const int blk = blockIdx.x;               // 0..1023
  const int b = blk / (LSEQ / 8);
  const int r0 = (blk % (LSEQ / 8)) * 8;
  const int t = threadIdx.x;
  for (int r = 0; r < 8; ++r)
    q[r][t] = qk[((size_t)b * LSEQ + r0 + r) * DIM + t];
  __syncthreads();
  float acc[8] = {0.f, 0.f, 0.f, 0.f, 0.f, 0.f, 0.f, 0.f};
  const float* Wb = W + (size_t)b * DIM * DIM;
  for (int d = 0; d < DIM; ++d) {
    const float w = Wb[d * DIM + t];
#pragma unroll
    for (int r = 0; r < 8; ++r) acc[r] = fmaf(q[r][d], w, acc[r]);
  }
  for (int r = 0; r < 8; ++r)
    g_R[((size_t)b * LSEQ + r0 + r) * DIM + t] = acc[r];
  __syncthreads();  // all q reads done -> safe to overwrite
  for (int r = 0; r < 8; ++r) q[r][t] = acc[r];
  __syncthreads();
  const int w = t >> 6, lane = t & 63;
#pragma unroll
  for (int rr = 0; rr < 2; ++rr) {
    const int r = w * 2 + rr;
    const float4 x = *(const float4*)&q[r][lane * 4];
    float s = x.x * x.x + x.y * x.y + x.z * x.z + x.w * x.w;
    for (int o = 32; o > 0; o >>= 1) s += __shfl_xor(s, o);
    if (lane == 0) g_xsq[(size_t)b * LSEQ + r0 + r] = s;
  }
}

// Persistent k-means: 64 blocks (block = chunk = cluster). Round-4 fp chains
// verbatim -> bit-identical trajectory. Cross-block data via SC1 coherent
// scalar ops; read-only g_R/g_xsq stay on the cached path (L2 never flushed).
__global__ void __launch_bounds__(256) k_kmeans(InitIdx ii) {
  __shared__ float Cs[DIM * KC];      // 64 KB transposed Cs[d][k]
  __shared__ float Xs[64 * XPITCH];   // 66.56 KB (padded rows)
  __shared__ int idx_s[128];
  __shared__ float red[256];
  const int t = threadIdx.x;
  const int c = blockIdx.x;           // chunk 0..63 (also cluster id for upB)
  const int p0 = c * 128;
  const int ptg = t >> 4;             // 0..15 -> 4-point group
  const int ctg = t & 15;             // 0..15 -> 4-cluster group
  const int ct = ctg * 4;

  // ---- init centroid k=c (exact round-4 chain) ----
  float myc;                          // this block's centroid component (dim t)
  {
    const float cv = g_R[(size_t)ii.v[c] * DIM + t];
    myc = cv;
    coh_st(&g_centT[t * KC + c], cv);
    red[t] = cv * cv;
    __syncthreads();
    for (int o = 128; o > 0; o >>= 1) {
      if (t < o) red[t] += red[t + o];
      __syncthreads();
    }
    if (t == 0) coh_st(&g_csq[c], red[0]);
  }
  grid_barrier();

  for (int it = 0; it <= KM_ITERS; ++it) {
    const bool final_pass = (it == KM_ITERS);

    // ---- load Cs from coherent centT (same values/layout as round 4) ----
    for (int idx = t; idx < DIM * KC; idx += 256) Cs[idx] = coh_ld(&g_centT[idx]);
    const float cs0 = coh_ld(&g_csq[ct + 0]);
    const float cs1 = coh_ld(&g_csq[ct + 1]);
    const float cs2 = coh_ld(&g_csq[ct + 2]);
    const float cs3 = coh_ld(&g_csq[ct + 3]);

    // ---- assign two 64-point halves (exact round-4 fmaf/argmin chains) ----
    for (int h = 0; h < 2; ++h) {
      __syncthreads();  // protect Xs reuse (and cover Cs load on h==0)
      for (int idx = t; idx < 64 * (DIM / 4); idx += 256) {
        const int r = idx >> 6;       // row 0..63
        const int dq = idx & 63;      // float4 index
        *(float4*)&Xs[r * XPITCH + dq * 4] =
            *(const float4*)(g_R + (size_t)(p0 + h * 64 + r) * DIM + dq * 4);
      }
      __syncthreads();

      float acc[4][4];
#pragma unroll
      for (int r = 0; r < 4; ++r)
#pragma unroll
        for (int j = 0; j < 4; ++j) acc[r][j] = 0.f;

#pragma unroll 4
      for (int d = 0; d < DIM; d += 4) {
        const float4 cv0 = *(const float4*)&Cs[(d + 0) * 64 + ct];
        const float4 cv1 = *(const float4*)&Cs[(d + 1) * 64 + ct];
        const float4 cv2 = *(const float4*)&Cs[(d + 2) * 64 + ct];
        const float4 cv3 = *(const float4*)&Cs[(d + 3) * 64 + ct];
#pragma unroll
        for (int r = 0; r < 4; ++r) {
          const float4 x = *(const float4*)&Xs[(ptg * 4 + r) * XPITCH + d];
          acc[r][0] = fmaf(x.x, cv0.x, fmaf(x.y, cv1.x, fmaf(x.z, cv2.x, fmaf(x.w, cv3.x, acc[r][0]))));
          acc[r][1] = fmaf(x.x, cv0.y, fmaf(x.y, cv1.y, fmaf(x.z, cv2.y, fmaf(x.w, cv3.y, acc[r][1]))));
          acc[r][2] = fmaf(x.x, cv0.z, fmaf(x.y, cv1.z, fmaf(x.z, cv2.z, fmaf(x.w, cv3.z, acc[r][2]))));
          acc[r][3] = fmaf(x.x, cv0.w, fmaf(x.y, cv1.w, fmaf(x.z, cv2.w, fmaf(x.w, cv3.w, acc[r][3]))));
        }
      }

#pragma unroll
      for (int r = 0; r < 4; ++r) {
        const int pl = h * 64 + ptg * 4 + r;
        const float xs = g_xsq[p0 + pl];
        float best = 3.4e38f;
        int bk = 0;
        {
          float v;
          v = (xs - 2.0f * acc[r][0]) + cs0; if (v < best) { best = v; bk = ct + 0; }
          v = (xs - 2.0f * acc[r][1]) + cs1; if (v < best) { best = v; bk = ct + 1; }
          v = (xs - 2.0f * acc[r][2]) + cs2; if (v < best) { best = v; bk = ct + 2; }
          v = (xs - 2.0f * acc[r][3]) + cs3; if (v < best) { best = v; bk = ct + 3; }
        }
#pragma unroll
        for (int o = 1; o < 16; o <<= 1) {
          const float ov = __shfl_xor(best, o);
          const int obk = __shfl_xor(bk, o);
          if (ov < best || (ov == best && obk < bk)) { best = ov; bk = obk; }
        }
        if (ctg == 0) {
          idx_s[pl] = bk;
          if (final_pass) g_idx[p0 + pl] = bk;
        }
      }
    }
    if (final_pass) break;

    // ---- upA (exact round-4 chain: pl 0..63 from g_R, 64..127 from Xs) ----
    {
      __syncthreads();
      const int k = t >> 2;   // cluster 0..63
      const int dg = t & 3;   // dims dg*64 .. dg*64+63
      float4 s[16];
#pragma unroll
      for (int q = 0; q < 16; ++q) s[q] = make_float4(0.f, 0.f, 0.f, 0.f);
      int cnt = 0;
      for (int pl = 0; pl < 64; ++pl) {
        if (idx_s[pl] == k) {
          const float4* row = (const float4*)(g_R + (size_t)(p0 + pl) * DIM + dg * 64);
#pragma unroll
          for (int q = 0; q < 16; ++q) {
            const float4 x = row[q];
            s[q].x += x.x; s[q].y += x.y; s[q].z += x.z; s[q].w += x.w;
          }
          cnt++;
        }
      }
      for (int pl = 64; pl < 128; ++pl) {
        if (idx_s[pl] == k) {
          const float4* row = (const float4*)(&Xs[(pl - 64) * XPITCH + dg * 64]);
#pragma unroll
          for (int q = 0; q < 16; ++q) {
            const float4 x = row[q];
            s[q].x += x.x; s[q].y += x.y; s[q].z += x.z; s[q].w += x.w;
          }
          cnt++;
        }
      }
      float* out = &g_part[c][k][dg * 64];
#pragma unroll
      for (int q = 0; q < 16; ++q) {
        coh_st(out + q * 4 + 0, s[q].x);
        coh_st(out + q * 4 + 1, s[q].y);
        coh_st(out + q * 4 + 2, s[q].z);
        coh_st(out + q * 4 + 3, s[q].w);
      }
      if (dg == 0) coh_sti(&g_pcnt[c][k], cnt);
    }
    grid_barrier();  // A: all g_part/g_pcnt visible (SC1 + vmcnt drain)

    // ---- upB for cluster c (exact round-4 chain; oldc carried in register) --
    {
      float s = 0.f;
#pragma unroll 4
      for (int ch = 0; ch < NCHUNK; ++ch) s += coh_ld(&g_part[ch][c][t]);
      int cnt = 0;
#pragma unroll 4
      for (int ch = 0; ch < NCHUNK; ++ch) cnt += coh_ldi(&g_pcnt[ch][c]);
      const float nc = (cnt > 0) ? (s / (float)cnt) : myc;
      myc = nc;
      coh_st(&g_centT[t * KC + c], nc);
      red[t] = nc * nc;
      __syncthreads();
      for (int o = 128; o > 0; o >>= 1) {
        if (t < o) red[t] += red[t + o];
        __syncthreads();
      }
      if (t == 0) coh_st(&g_csq[c], red[0]);
    }
    grid_barrier();  // B: new centroids visible
  }
}

// mask write: out[b,h,i,j] = (cid[b,i]==cid[b,j]) ? 0 : -10000. 16 rows/block.
__global__ void __launch_bounds__(256) k_mask(float* __restrict__ out, int H) {
  const int blk = blockIdx.x;
  const int tiles = LSEQ / 16;  // 256
  const int b = blk / (H * tiles);
  const int h = (blk / tiles) % H;
  const int tile = blk % tiles;
  const int t = threadIdx.x;
  __shared__ int cid[LSEQ];  // 16 KB
  for (int j = t; j < LSEQ; j += 256) cid[j] = g_idx[b * LSEQ + j];
  __syncthreads();
  const size_t base = ((size_t)(b * H + h) * LSEQ + (size_t)tile * 16) * LSEQ;
  for (int r = 0; r < 16; ++r) {
    const int my = cid[tile * 16 + r];
    float4* orow = (float4*)(out + base + (size_t)r * LSEQ);
#pragma unroll
    for (int s = 0; s < 4; ++s) {
      const int c4 = s * 256 + t;  // float4 index within row
      const int j = c4 * 4;
      float4 v;
      v.x = (cid[j + 0] == my) ? 0.f : -10000.f;
      v.y = (cid[j + 1] == my) ? 0.f : -10000.f;
      v.z = (cid[j + 2] == my) ? 0.f : -10000.f;
      v.w = (cid[j + 3] == my) ? 0.f : -10000.f;
      orow[c4] = v;
    }
  }
}

// ---------------- launch -----------------------------------------------------
extern "C" void kernel_launch(void* const* d_in, const int* in_sizes, int n_in,
                              void* d_out, int out_size, void* d_ws, size_t ws_size,
                              hipStream_t stream) {
  const float* qk = (const float*)d_in[0];
  const float* W = (const float*)d_in[1];
  const int H = out_size / (NB * LSEQ * LSEQ);  // 8

  const InitIdx ii = compute_init_indices();  // pure host integer math

  k_R_xsq<<<NB * (LSEQ / 8), 256, 0, stream>>>(qk, W);
  k_kmeans<<<NBLK, 256, 0, stream>>>(ii);
  k_mask<<<NB * H * (LSEQ / 16), 256, 0, stream>>>((float*)d_out, H);
}

// Round 7
// 938.588 us; speedup vs baseline: 1.3840x; 1.3840x over previous
//
#include <hip/hip_runtime.h>
#include <stdint.h>
#include <stddef.h>
#include <vector>
#include <algorithm>
#include <utility>

// Problem constants (B=2, L=4096, D=256, H=8, K=sqrt(L)=64, 10 Lloyd iters)
#define NPTS 8192
#define DIM  256
#define KC   64
#define LSEQ 4096
#define NB   2
#define KM_ITERS 10
#define NCHUNK 64     // 8192/128 points per summation chunk (bit-exact structure)
#define NBLK 64       // persistent kmeans blocks (block = chunk = cluster)
#define XPITCH 260    // padded LDS row for X tile (breaks bank aliasing)

// JAX threefry mode: 1 = partitionable (default since jax 0.4.36), 0 = original
#define JAX_THREEFRY_PARTITIONABLE 1

// ---------------- static device scratch (fully rewritten every call) --------
__device__ float g_R[NPTS * DIM];          // 8 MB   rotated points (read-only in kmeans)
__device__ float g_xsq[NPTS];              // 32 KB  per-point squared norm
__device__ float g_centT[DIM * KC];        // 64 KB  centroids transposed [d][k]
__device__ float g_csq[KC];                // per-centroid squared norm
__device__ int   g_idx[NPTS];              // final assignments (= cid)
__device__ float g_part[NCHUNK][KC][DIM];  // 4 MB   chunked segment sums
__device__ int   g_pcnt[NCHUNK][KC];       // chunked counts

// Monotone ticket grid barrier state (persists across replays; never reset —
// tickets/releases only grow, so behavior is identical every launch).
__device__ unsigned g_ticket  = 0;
__device__ unsigned g_release = 0;

// Minimal-invalidate grid barrier. Data travels on the normal cached path:
//  - arrival ACQ_REL fetch_add: ONE L2 writeback (release) publishes this
//    block's dirty lines to the L3 coherence point.
//  - RELAXED poll: no cache maintenance while spinning (the round-4 version
//    polled with ACQUIRE -> one L2 invalidate per poll -> invalidate storm).
//  - ONE final ACQUIRE load: single L2 invalidate so subsequent cached reads
//    refetch cross-XCD data from L3.
__device__ __forceinline__ void grid_barrier() {
  __syncthreads();
  if (threadIdx.x == 0) {
    const unsigned my = __hip_atomic_fetch_add(&g_ticket, 1u, __ATOMIC_ACQ_REL,
                                               __HIP_MEMORY_SCOPE_AGENT);
    const unsigned target = (my / NBLK + 1u) * NBLK;
    if (my % NBLK == NBLK - 1u) {
      __hip_atomic_store(&g_release, target, __ATOMIC_RELEASE,
                         __HIP_MEMORY_SCOPE_AGENT);
    } else {
      while (__hip_atomic_load(&g_release, __ATOMIC_RELAXED,
                               __HIP_MEMORY_SCOPE_AGENT) < target) {
        __builtin_amdgcn_s_sleep(8);
      }
    }
    (void)__hip_atomic_load(&g_release, __ATOMIC_ACQUIRE,
                            __HIP_MEMORY_SCOPE_AGENT);  // single inv
  }
  __syncthreads();
}

// ---------------- host threefry2x32 (exact JAX semantics) -------------------
static inline uint32_t rotl32(uint32_t x, int r) { return (x << r) | (x >> (32 - r)); }

static void threefry2x32(uint32_t k0, uint32_t k1, uint32_t x0, uint32_t x1,
                         uint32_t& o0, uint32_t& o1) {
  const uint32_t ks0 = k0, ks1 = k1, ks2 = k0 ^ k1 ^ 0x1BD11BDAu;
  const int r1[4] = {13, 15, 26, 6}, r2[4] = {17, 29, 16, 24};
  x0 += ks0; x1 += ks1;
  for (int i = 0; i < 4; ++i) { x0 += x1; x1 = rotl32(x1, r1[i]); x1 ^= x0; }
  x0 += ks1; x1 += ks2 + 1u;
  for (int i = 0; i < 4; ++i) { x0 += x1; x1 = rotl32(x1, r2[i]); x1 ^= x0; }
  x0 += ks2; x1 += ks0 + 2u;
  for (int i = 0; i < 4; ++i) { x0 += x1; x1 = rotl32(x1, r1[i]); x1 ^= x0; }
  x0 += ks0; x1 += ks1 + 3u;
  for (int i = 0; i < 4; ++i) { x0 += x1; x1 = rotl32(x1, r2[i]); x1 ^= x0; }
  x0 += ks1; x1 += ks2 + 4u;
  for (int i = 0; i < 4; ++i) { x0 += x1; x1 = rotl32(x1, r1[i]); x1 ^= x0; }
  x0 += ks2; x1 += ks0 + 5u;
  o0 = x0; o1 = x1;
}

struct InitIdx { int v[KC]; };

// jax.random.choice(key(42), 8192, (64,), replace=False)
//  = permutation(key, arange(8192))[:64]  (2-round threefry shuffle)
static InitIdx compute_init_indices() {
  uint32_t k0 = 0u, k1 = 42u;  // jax.random.key(42) -> [0, 42]
  std::vector<int> val(NPTS);
  for (int i = 0; i < NPTS; ++i) val[i] = i;
  std::vector<std::pair<uint32_t, int>> kv(NPTS);
  for (int round = 0; round < 2; ++round) {
    uint32_t nk0, nk1, sk0, sk1;
#if JAX_THREEFRY_PARTITIONABLE
    threefry2x32(k0, k1, 0u, 0u, nk0, nk1);
    threefry2x32(k0, k1, 0u, 1u, sk0, sk1);
    k0 = nk0; k1 = nk1;
    for (int i = 0; i < NPTS; ++i) {
      uint32_t o0, o1;
      threefry2x32(sk0, sk1, 0u, (uint32_t)i, o0, o1);
      kv[i] = std::make_pair(o0 ^ o1, val[i]);
    }
#else
    uint32_t a0, a1, b0, b1;
    threefry2x32(k0, k1, 0u, 2u, a0, a1);
    threefry2x32(k0, k1, 1u, 3u, b0, b1);
    nk0 = a0; nk1 = b0; sk0 = a1; sk1 = b1;
    k0 = nk0; k1 = nk1;
    for (int i = 0; i < NPTS / 2; ++i) {
      uint32_t o0, o1;
      threefry2x32(sk0, sk1, (uint32_t)i, (uint32_t)(i + NPTS / 2), o0, o1);
      kv[i] = std::make_pair(o0, 0);
      kv[i + NPTS / 2] = std::make_pair(o1, 0);
    }
    for (int i = 0; i < NPTS; ++i) kv[i].second = val[i];
#endif
    std::stable_sort(kv.begin(), kv.end(),
                     [](const std::pair<uint32_t, int>& a,
                        const std::pair<uint32_t, int>& b) { return a.first < b.first; });
    for (int i = 0; i < NPTS; ++i) val[i] = kv[i].second;
  }
  InitIdx ii;
  for (int k = 0; k < KC; ++k) ii.v[k] = val[k];
  return ii;
}

// ---------------- kernels ---------------------------------------------------

// Fused R-GEMM + xsq. R[b,l,e] = sum_d qk[b,l,d]*W[b,d,e]; 8 rows per block.
// xsq: per-lane float4 square-sum over dims 4t..4t+3, then 64-lane butterfly.
__global__ void __launch_bounds__(256) k_R_xsq(const float* __restrict__ qk,
                                               const float* __restrict__ W) {
  __shared__ float q[8][DIM];
  const int blk = blockIdx.x;               // 0..1023
  const int b = blk / (LSEQ / 8);
  const int r0 = (blk % (LSEQ / 8)) * 8;
  const int t = threadIdx.x;
  for (int r = 0; r < 8; ++r)
    q[r][t] = qk[((size_t)b * LSEQ + r0 + r) * DIM + t];
  __syncthreads();
  float acc[8] = {0.f, 0.f, 0.f, 0.f, 0.f, 0.f, 0.f, 0.f};
  const float* Wb = W + (size_t)b * DIM * DIM;
  for (int d = 0; d < DIM; ++d) {
    const float w = Wb[d * DIM + t];
#pragma unroll
    for (int r = 0; r < 8; ++r) acc[r] = fmaf(q[r][d], w, acc[r]);
  }
  for (int r = 0; r < 8; ++r)
    g_R[((size_t)b * LSEQ + r0 + r) * DIM + t] = acc[r];
  __syncthreads();  // all q reads done -> safe to overwrite
  for (int r = 0; r < 8; ++r) q[r][t] = acc[r];
  __syncthreads();
  const int w = t >> 6, lane = t & 63;
#pragma unroll
  for (int rr = 0; rr < 2; ++rr) {
    const int r = w * 2 + rr;
    const float4 x = *(const float4*)&q[r][lane * 4];
    float s = x.x * x.x + x.y * x.y + x.z * x.z + x.w * x.w;
    for (int o = 32; o > 0; o >>= 1) s += __shfl_xor(s, o);
    if (lane == 0) g_xsq[(size_t)b * LSEQ + r0 + r] = s;
  }
}

// Persistent k-means: 64 blocks (block = chunk = cluster). Round-4 fp chains
// verbatim -> bit-identical trajectory. All data on the normal cached path;
// cross-XCD visibility provided by the barrier's release-wb / acquire-inv.
__global__ void __launch_bounds__(256) k_kmeans(InitIdx ii) {
  __shared__ float Cs[DIM * KC];      // 64 KB transposed Cs[d][k]
  __shared__ float Xs[64 * XPITCH];   // 66.56 KB (padded rows)
  __shared__ int idx_s[128];
  __shared__ float red[256];
  const int t = threadIdx.x;
  const int c = blockIdx.x;           // chunk 0..63 (also cluster id for upB)
  const int p0 = c * 128;
  const int ptg = t >> 4;             // 0..15 -> 4-point group
  const int ctg = t & 15;             // 0..15 -> 4-cluster group
  const int ct = ctg * 4;

  // ---- init centroid k=c (exact round-4 chain) ----
  float myc;                          // this block's centroid component (dim t)
  {
    const float cv = g_R[(size_t)ii.v[c] * DIM + t];
    myc = cv;
    g_centT[t * KC + c] = cv;
    red[t] = cv * cv;
    __syncthreads();
    for (int o = 128; o > 0; o >>= 1) {
      if (t < o) red[t] += red[t + o];
      __syncthreads();
    }
    if (t == 0) g_csq[c] = red[0];
  }
  grid_barrier();

  for (int it = 0; it <= KM_ITERS; ++it) {
    const bool final_pass = (it == KM_ITERS);

    // ---- load Cs from centT (coalesced cached loads; fresh after barrier) --
    {
      float4* Cs4 = (float4*)Cs;
      const float4* T4 = (const float4*)g_centT;
      for (int idx = t; idx < (DIM * KC) / 4; idx += 256) Cs4[idx] = T4[idx];
    }
    const float cs0 = g_csq[ct + 0];
    const float cs1 = g_csq[ct + 1];
    const float cs2 = g_csq[ct + 2];
    const float cs3 = g_csq[ct + 3];

    // ---- assign two 64-point halves (exact round-4 fmaf/argmin chains) ----
    for (int h = 0; h < 2; ++h) {
      __syncthreads();  // protect Xs reuse (and cover Cs load on h==0)
      for (int idx = t; idx < 64 * (DIM / 4); idx += 256) {
        const int r = idx >> 6;       // row 0..63
        const int dq = idx & 63;      // float4 index
        *(float4*)&Xs[r * XPITCH + dq * 4] =
            *(const float4*)(g_R + (size_t)(p0 + h * 64 + r) * DIM + dq * 4);
      }
      __syncthreads();

      float acc[4][4];
#pragma unroll
      for (int r = 0; r < 4; ++r)
#pragma unroll
        for (int j = 0; j < 4; ++j) acc[r][j] = 0.f;

#pragma unroll 4
      for (int d = 0; d < DIM; d += 4) {
        const float4 cv0 = *(const float4*)&Cs[(d + 0) * 64 + ct];
        const float4 cv1 = *(const float4*)&Cs[(d + 1) * 64 + ct];
        const float4 cv2 = *(const float4*)&Cs[(d + 2) * 64 + ct];
        const float4 cv3 = *(const float4*)&Cs[(d + 3) * 64 + ct];
#pragma unroll
        for (int r = 0; r < 4; ++r) {
          const float4 x = *(const float4*)&Xs[(ptg * 4 + r) * XPITCH + d];
          acc[r][0] = fmaf(x.x, cv0.x, fmaf(x.y, cv1.x, fmaf(x.z, cv2.x, fmaf(x.w, cv3.x, acc[r][0]))));
          acc[r][1] = fmaf(x.x, cv0.y, fmaf(x.y, cv1.y, fmaf(x.z, cv2.y, fmaf(x.w, cv3.y, acc[r][1]))));
          acc[r][2] = fmaf(x.x, cv0.z, fmaf(x.y, cv1.z, fmaf(x.z, cv2.z, fmaf(x.w, cv3.z, acc[r][2]))));
          acc[r][3] = fmaf(x.x, cv0.w, fmaf(x.y, cv1.w, fmaf(x.z, cv2.w, fmaf(x.w, cv3.w, acc[r][3]))));
        }
      }

#pragma unroll
      for (int r = 0; r < 4; ++r) {
        const int pl = h * 64 + ptg * 4 + r;
        const float xs = g_xsq[p0 + pl];
        float best = 3.4e38f;
        int bk = 0;
        {
          float v;
          v = (xs - 2.0f * acc[r][0]) + cs0; if (v < best) { best = v; bk = ct + 0; }
          v = (xs - 2.0f * acc[r][1]) + cs1; if (v < best) { best = v; bk = ct + 1; }
          v = (xs - 2.0f * acc[r][2]) + cs2; if (v < best) { best = v; bk = ct + 2; }
          v = (xs - 2.0f * acc[r][3]) + cs3; if (v < best) { best = v; bk = ct + 3; }
        }
#pragma unroll
        for (int o = 1; o < 16; o <<= 1) {
          const float ov = __shfl_xor(best, o);
          const int obk = __shfl_xor(bk, o);
          if (ov < best || (ov == best && obk < bk)) { best = ov; bk = obk; }
        }
        if (ctg == 0) {
          idx_s[pl] = bk;
          if (final_pass) g_idx[p0 + pl] = bk;
        }
      }
    }
    if (final_pass) break;

    // ---- upA (exact round-4 chain: pl 0..63 from g_R, 64..127 from Xs) ----
    {
      __syncthreads();
      const int k = t >> 2;   // cluster 0..63
      const int dg = t & 3;   // dims dg*64 .. dg*64+63
      float4 s[16];
#pragma unroll
      for (int q = 0; q < 16; ++q) s[q] = make_float4(0.f, 0.f, 0.f, 0.f);
      int cnt = 0;
      for (int pl = 0; pl < 64; ++pl) {
        if (idx_s[pl] == k) {
          const float4* row = (const float4*)(g_R + (size_t)(p0 + pl) * DIM + dg * 64);
#pragma unroll
          for (int q = 0; q < 16; ++q) {
            const float4 x = row[q];
            s[q].x += x.x; s[q].y += x.y; s[q].z += x.z; s[q].w += x.w;
          }
          cnt++;
        }
      }
      for (int pl = 64; pl < 128; ++pl) {
        if (idx_s[pl] == k) {
          const float4* row = (const float4*)(&Xs[(pl - 64) * XPITCH + dg * 64]);
#pragma unroll
          for (int q = 0; q < 16; ++q) {
            const float4 x = row[q];
            s[q].x += x.x; s[q].y += x.y; s[q].z += x.z; s[q].w += x.w;
          }
          cnt++;
        }
      }
      float4* out = (float4*)(&g_part[c][k][dg * 64]);
#pragma unroll
      for (int q = 0; q < 16; ++q) out[q] = s[q];
      if (dg == 0) g_pcnt[c][k] = cnt;
    }
    grid_barrier();  // A: g_part/g_pcnt published (release-wb) + L2 inv'd

    // ---- upB for cluster c (exact round-4 chain; oldc carried in register) --
    {
      float s = 0.f;
#pragma unroll 4
      for (int ch = 0; ch < NCHUNK; ++ch) s += g_part[ch][c][t];
      int cnt = 0;
#pragma unroll 4
      for (int ch = 0; ch < NCHUNK; ++ch) cnt += g_pcnt[ch][c];
      const float nc = (cnt > 0) ? (s / (float)cnt) : myc;
      myc = nc;
      g_centT[t * KC + c] = nc;
      red[t] = nc * nc;
      __syncthreads();
      for (int o = 128; o > 0; o >>= 1) {
        if (t < o) red[t] += red[t + o];
        __syncthreads();
      }
      if (t == 0) g_csq[c] = red[0];
    }
    grid_barrier();  // B: new centroids visible
  }
}

// mask write: out[b,h,i,j] = (cid[b,i]==cid[b,j]) ? 0 : -10000. 16 rows/block.
__global__ void __launch_bounds__(256) k_mask(float* __restrict__ out, int H) {
  const int blk = blockIdx.x;
  const int tiles = LSEQ / 16;  // 256
  const int b = blk / (H * tiles);
  const int h = (blk / tiles) % H;
  const int tile = blk % tiles;
  const int t = threadIdx.x;
  __shared__ int cid[LSEQ];  // 16 KB
  for (int j = t; j < LSEQ; j += 256) cid[j] = g_idx[b * LSEQ + j];
  __syncthreads();
  const size_t base = ((size_t)(b * H + h) * LSEQ + (size_t)tile * 16) * LSEQ;
  for (int r = 0; r < 16; ++r) {
    const int my = cid[tile * 16 + r];
    float4* orow = (float4*)(out + base + (size_t)r * LSEQ);
#pragma unroll
    for (int s = 0; s < 4; ++s) {
      const int c4 = s * 256 + t;  // float4 index within row
      const int j = c4 * 4;
      float4 v;
      v.x = (cid[j + 0] == my) ? 0.f : -10000.f;
      v.y = (cid[j + 1] == my) ? 0.f : -10000.f;
      v.z = (cid[j + 2] == my) ? 0.f : -10000.f;
      v.w = (cid[j + 3] == my) ? 0.f : -10000.f;
      orow[c4] = v;
    }
  }
}

// ---------------- launch -----------------------------------------------------
extern "C" void kernel_launch(void* const* d_in, const int* in_sizes, int n_in,
                              void* d_out, int out_size, void* d_ws, size_t ws_size,
                              hipStream_t stream) {
  const float* qk = (const float*)d_in[0];
  const float* W = (const float*)d_in[1];
  const int H = out_size / (NB * LSEQ * LSEQ);  // 8

  const InitIdx ii = compute_init_indices();  // pure host integer math

  k_R_xsq<<<NB * (LSEQ / 8), 256, 0, stream>>>(qk, W);
  k_kmeans<<<NBLK, 256, 0, stream>>>(ii);
  k_mask<<<NB * H * (LSEQ / 16), 256, 0, stream>>>((float*)d_out, H);
}

// Round 8
// 905.507 us; speedup vs baseline: 1.4346x; 1.0365x over previous
//
#include <hip/hip_runtime.h>
#include <stdint.h>
#include <stddef.h>
#include <vector>
#include <algorithm>
#include <utility>

// Problem constants (B=2, L=4096, D=256, H=8, K=sqrt(L)=64, 10 Lloyd iters)
#define NPTS 8192
#define DIM  256
#define KC   64
#define LSEQ 4096
#define NB   2
#define KM_ITERS 10
#define NCHUNK 64     // 8192/128 points per summation chunk (bit-exact structure)
#define NBLK 64       // persistent kmeans blocks (block = chunk = cluster)
#define XPITCH 260    // padded LDS row for X tile (breaks bank aliasing)

// JAX threefry mode: 1 = partitionable (default since jax 0.4.36), 0 = original
#define JAX_THREEFRY_PARTITIONABLE 1

// ---------------- static device scratch (fully rewritten every call) --------
__device__ float g_R[NPTS * DIM];          // 8 MB   rotated points (read-only in kmeans)
__device__ float g_xsq[NPTS];              // 32 KB  per-point squared norm
__device__ float g_centT[DIM * KC];        // 64 KB  centroids transposed [d][k]
__device__ float g_csq[KC];                // per-centroid squared norm
__device__ int   g_idx[NPTS];              // final assignments (= cid)
__device__ float g_part[NCHUNK][KC][DIM];  // 4 MB   chunked segment sums
__device__ int   g_pcnt[NCHUNK][KC];       // chunked counts

// Flag-tree grid barrier state. Monotone across graph replays: every launch
// executes exactly the same number of barriers, so flag values are a pure
// function of replay count; each block reads its own flag at entry as base.
// One padded cache line per block: parallel arrival stores, no RMW contention.
__device__ unsigned g_arrive[NBLK * 16];   // block c uses g_arrive[c*16]
__device__ unsigned g_release2;            // release word (monotone)

// Arrival: release-store (one L2 writeback publishes this block's dirty lines).
// Block 0: 64 threads poll the 64 flags in parallel (relaxed sc1, distinct
// lines), then one release-store to g_release2. Others: poll release word
// relaxed, then one acquire load (single L2 invalidate).
__device__ __forceinline__ void grid_barrier(int c, unsigned target) {
  __syncthreads();  // drains vmcnt: all block stores are at least in L2
  const int t = threadIdx.x;
  if (t == 0) {
    __hip_atomic_store(&g_arrive[c * 16], target, __ATOMIC_RELEASE,
                       __HIP_MEMORY_SCOPE_AGENT);
  }
  if (c == 0) {
    if (t < NBLK) {
      while (__hip_atomic_load(&g_arrive[t * 16], __ATOMIC_RELAXED,
                               __HIP_MEMORY_SCOPE_AGENT) < target) {
        __builtin_amdgcn_s_sleep(1);
      }
    }
    __syncthreads();
    if (t == 0) {
      __hip_atomic_store(&g_release2, target, __ATOMIC_RELEASE,
                         __HIP_MEMORY_SCOPE_AGENT);
      (void)__hip_atomic_load(&g_release2, __ATOMIC_ACQUIRE,
                              __HIP_MEMORY_SCOPE_AGENT);  // single inv
    }
  } else {
    if (t == 0) {
      while (__hip_atomic_load(&g_release2, __ATOMIC_RELAXED,
                               __HIP_MEMORY_SCOPE_AGENT) < target) {
        __builtin_amdgcn_s_sleep(2);
      }
      (void)__hip_atomic_load(&g_release2, __ATOMIC_ACQUIRE,
                              __HIP_MEMORY_SCOPE_AGENT);  // single inv
    }
  }
  __syncthreads();
}

// ---------------- host threefry2x32 (exact JAX semantics) -------------------
static inline uint32_t rotl32(uint32_t x, int r) { return (x << r) | (x >> (32 - r)); }

static void threefry2x32(uint32_t k0, uint32_t k1, uint32_t x0, uint32_t x1,
                         uint32_t& o0, uint32_t& o1) {
  const uint32_t ks0 = k0, ks1 = k1, ks2 = k0 ^ k1 ^ 0x1BD11BDAu;
  const int r1[4] = {13, 15, 26, 6}, r2[4] = {17, 29, 16, 24};
  x0 += ks0; x1 += ks1;
  for (int i = 0; i < 4; ++i) { x0 += x1; x1 = rotl32(x1, r1[i]); x1 ^= x0; }
  x0 += ks1; x1 += ks2 + 1u;
  for (int i = 0; i < 4; ++i) { x0 += x1; x1 = rotl32(x1, r2[i]); x1 ^= x0; }
  x0 += ks2; x1 += ks0 + 2u;
  for (int i = 0; i < 4; ++i) { x0 += x1; x1 = rotl32(x1, r1[i]); x1 ^= x0; }
  x0 += ks0; x1 += ks1 + 3u;
  for (int i = 0; i < 4; ++i) { x0 += x1; x1 = rotl32(x1, r2[i]); x1 ^= x0; }
  x0 += ks1; x1 += ks2 + 4u;
  for (int i = 0; i < 4; ++i) { x0 += x1; x1 = rotl32(x1, r1[i]); x1 ^= x0; }
  x0 += ks2; x1 += ks0 + 5u;
  o0 = x0; o1 = x1;
}

struct InitIdx { int v[KC]; };

// jax.random.choice(key(42), 8192, (64,), replace=False)
//  = permutation(key, arange(8192))[:64]  (2-round threefry shuffle)
static InitIdx compute_init_indices() {
  uint32_t k0 = 0u, k1 = 42u;  // jax.random.key(42) -> [0, 42]
  std::vector<int> val(NPTS);
  for (int i = 0; i < NPTS; ++i) val[i] = i;
  std::vector<std::pair<uint32_t, int>> kv(NPTS);
  for (int round = 0; round < 2; ++round) {
    uint32_t nk0, nk1, sk0, sk1;
#if JAX_THREEFRY_PARTITIONABLE
    threefry2x32(k0, k1, 0u, 0u, nk0, nk1);
    threefry2x32(k0, k1, 0u, 1u, sk0, sk1);
    k0 = nk0; k1 = nk1;
    for (int i = 0; i < NPTS; ++i) {
      uint32_t o0, o1;
      threefry2x32(sk0, sk1, 0u, (uint32_t)i, o0, o1);
      kv[i] = std::make_pair(o0 ^ o1, val[i]);
    }
#else
    uint32_t a0, a1, b0, b1;
    threefry2x32(k0, k1, 0u, 2u, a0, a1);
    threefry2x32(k0, k1, 1u, 3u, b0, b1);
    nk0 = a0; nk1 = b0; sk0 = a1; sk1 = b1;
    k0 = nk0; k1 = nk1;
    for (int i = 0; i < NPTS / 2; ++i) {
      uint32_t o0, o1;
      threefry2x32(sk0, sk1, (uint32_t)i, (uint32_t)(i + NPTS / 2), o0, o1);
      kv[i] = std::make_pair(o0, 0);
      kv[i + NPTS / 2] = std::make_pair(o1, 0);
    }
    for (int i = 0; i < NPTS; ++i) kv[i].second = val[i];
#endif
    std::stable_sort(kv.begin(), kv.end(),
                     [](const std::pair<uint32_t, int>& a,
                        const std::pair<uint32_t, int>& b) { return a.first < b.first; });
    for (int i = 0; i < NPTS; ++i) val[i] = kv[i].second;
  }
  InitIdx ii;
  for (int k = 0; k < KC; ++k) ii.v[k] = val[k];
  return ii;
}

// ---------------- kernels ---------------------------------------------------

// Fused R-GEMM + xsq. R[b,l,e] = sum_d qk[b,l,d]*W[b,d,e]; 8 rows per block.
// xsq: per-lane float4 square-sum over dims 4t..4t+3, then 64-lane butterfly.
__global__ void __launch_bounds__(256) k_R_xsq(const float* __restrict__ qk,
                                               const float* __restrict__ W) {
  __shared__ float q[8][DIM];
  const int blk = blockIdx.x;               // 0..1023
  const int b = blk / (LSEQ / 8);
  const int r0 = (blk % (LSEQ / 8)) * 8;
  const int t = threadIdx.x;
  for (int r = 0; r < 8; ++r)
    q[r][t] = qk[((size_t)b * LSEQ + r0 + r) * DIM + t];
  __syncthreads();
  float acc[8] = {0.f, 0.f, 0.f, 0.f, 0.f, 0.f, 0.f, 0.f};
  const float* Wb = W + (size_t)b * DIM * DIM;
  for (int d = 0; d < DIM; ++d) {
    const float w = Wb[d * DIM + t];
#pragma unroll
    for (int r = 0; r < 8; ++r) acc[r] = fmaf(q[r][d], w, acc[r]);
  }
  for (int r = 0; r < 8; ++r)
    g_R[((size_t)b * LSEQ + r0 + r) * DIM + t] = acc[r];
  __syncthreads();  // all q reads done -> safe to overwrite
  for (int r = 0; r < 8; ++r) q[r][t] = acc[r];
  __syncthreads();
  const int w = t >> 6, lane = t & 63;
#pragma unroll
  for (int rr = 0; rr < 2; ++rr) {
    const int r = w * 2 + rr;
    const float4 x = *(const float4*)&q[r][lane * 4];
    float s = x.x * x.x + x.y * x.y + x.z * x.z + x.w * x.w;
    for (int o = 32; o > 0; o >>= 1) s += __shfl_xor(s, o);
    if (lane == 0) g_xsq[(size_t)b * LSEQ + r0 + r] = s;
  }
}

// Persistent k-means: 64 blocks (block = chunk = cluster). Round-4 fp chains
// verbatim -> bit-identical trajectory. Data on the normal cached path;
// cross-XCD visibility via the barrier's release-wb / acquire-inv.
__global__ void __launch_bounds__(256) k_kmeans(InitIdx ii) {
  __shared__ float Cs[DIM * KC];      // 64 KB transposed Cs[d][k]
  __shared__ float Xs[64 * XPITCH];   // 66.56 KB (padded rows)
  __shared__ int idx_s[128];
  __shared__ float red[256];
  __shared__ unsigned base_s;
  const int t = threadIdx.x;
  const int c = blockIdx.x;           // chunk 0..63 (also cluster id for upB)
  const int p0 = c * 128;
  const int ptg = t >> 4;             // 0..15 -> 4-point group
  const int ctg = t & 15;             // 0..15 -> 4-cluster group
  const int ct = ctg * 4;

  // base for this launch: own flag's last value (deterministic per replay)
  if (t == 0)
    base_s = __hip_atomic_load(&g_arrive[c * 16], __ATOMIC_RELAXED,
                               __HIP_MEMORY_SCOPE_AGENT);
  __syncthreads();
  const unsigned base = base_s;
  unsigned bar = 0;                   // barrier counter within this launch

  // ---- init centroid k=c (exact round-4 chain) ----
  float myc;                          // this block's centroid component (dim t)
  {
    const float cv = g_R[(size_t)ii.v[c] * DIM + t];
    myc = cv;
    g_centT[t * KC + c] = cv;
    red[t] = cv * cv;
    __syncthreads();
    for (int o = 128; o > 0; o >>= 1) {
      if (t < o) red[t] += red[t + o];
      __syncthreads();
    }
    if (t == 0) g_csq[c] = red[0];
  }
  grid_barrier(c, base + (++bar));

  for (int it = 0; it <= KM_ITERS; ++it) {
    const bool final_pass = (it == KM_ITERS);

    // ---- load Cs from centT (coalesced cached loads; fresh after barrier) --
    {
      float4* Cs4 = (float4*)Cs;
      const float4* T4 = (const float4*)g_centT;
      for (int idx = t; idx < (DIM * KC) / 4; idx += 256) Cs4[idx] = T4[idx];
    }
    const float cs0 = g_csq[ct + 0];
    const float cs1 = g_csq[ct + 1];
    const float cs2 = g_csq[ct + 2];
    const float cs3 = g_csq[ct + 3];

    // ---- assign two 64-point halves (exact round-4 fmaf/argmin chains) ----
    for (int h = 0; h < 2; ++h) {
      __syncthreads();  // protect Xs reuse (and cover Cs load on h==0)
      for (int idx = t; idx < 64 * (DIM / 4); idx += 256) {
        const int r = idx >> 6;       // row 0..63
        const int dq = idx & 63;      // float4 index
        *(float4*)&Xs[r * XPITCH + dq * 4] =
            *(const float4*)(g_R + (size_t)(p0 + h * 64 + r) * DIM + dq * 4);
      }
      __syncthreads();

      float acc[4][4];
#pragma unroll
      for (int r = 0; r < 4; ++r)
#pragma unroll
        for (int j = 0; j < 4; ++j) acc[r][j] = 0.f;

#pragma unroll 4
      for (int d = 0; d < DIM; d += 4) {
        const float4 cv0 = *(const float4*)&Cs[(d + 0) * 64 + ct];
        const float4 cv1 = *(const float4*)&Cs[(d + 1) * 64 + ct];
        const float4 cv2 = *(const float4*)&Cs[(d + 2) * 64 + ct];
        const float4 cv3 = *(const float4*)&Cs[(d + 3) * 64 + ct];
#pragma unroll
        for (int r = 0; r < 4; ++r) {
          const float4 x = *(const float4*)&Xs[(ptg * 4 + r) * XPITCH + d];
          acc[r][0] = fmaf(x.x, cv0.x, fmaf(x.y, cv1.x, fmaf(x.z, cv2.x, fmaf(x.w, cv3.x, acc[r][0]))));
          acc[r][1] = fmaf(x.x, cv0.y, fmaf(x.y, cv1.y, fmaf(x.z, cv2.y, fmaf(x.w, cv3.y, acc[r][1]))));
          acc[r][2] = fmaf(x.x, cv0.z, fmaf(x.y, cv1.z, fmaf(x.z, cv2.z, fmaf(x.w, cv3.z, acc[r][2]))));
          acc[r][3] = fmaf(x.x, cv0.w, fmaf(x.y, cv1.w, fmaf(x.z, cv2.w, fmaf(x.w, cv3.w, acc[r][3]))));
        }
      }

#pragma unroll
      for (int r = 0; r < 4; ++r) {
        const int pl = h * 64 + ptg * 4 + r;
        const float xs = g_xsq[p0 + pl];
        float best = 3.4e38f;
        int bk = 0;
        {
          float v;
          v = (xs - 2.0f * acc[r][0]) + cs0; if (v < best) { best = v; bk = ct + 0; }
          v = (xs - 2.0f * acc[r][1]) + cs1; if (v < best) { best = v; bk = ct + 1; }
          v = (xs - 2.0f * acc[r][2]) + cs2; if (v < best) { best = v; bk = ct + 2; }
          v = (xs - 2.0f * acc[r][3]) + cs3; if (v < best) { best = v; bk = ct + 3; }
        }
#pragma unroll
        for (int o = 1; o < 16; o <<= 1) {
          const float ov = __shfl_xor(best, o);
          const int obk = __shfl_xor(bk, o);
          if (ov < best || (ov == best && obk < bk)) { best = ov; bk = obk; }
        }
        if (ctg == 0) {
          idx_s[pl] = bk;
          if (final_pass) g_idx[p0 + pl] = bk;
        }
      }
    }
    if (final_pass) break;

    // ---- upA (exact round-4 chain: pl 0..63 from g_R, 64..127 from Xs) ----
    {
      __syncthreads();
      const int k = t >> 2;   // cluster 0..63
      const int dg = t & 3;   // dims dg*64 .. dg*64+63
      float4 s[16];
#pragma unroll
      for (int q = 0; q < 16; ++q) s[q] = make_float4(0.f, 0.f, 0.f, 0.f);
      int cnt = 0;
      for (int pl = 0; pl < 64; ++pl) {
        if (idx_s[pl] == k) {
          const float4* row = (const float4*)(g_R + (size_t)(p0 + pl) * DIM + dg * 64);
#pragma unroll
          for (int q = 0; q < 16; ++q) {
            const float4 x = row[q];
            s[q].x += x.x; s[q].y += x.y; s[q].z += x.z; s[q].w += x.w;
          }
          cnt++;
        }
      }
      for (int pl = 64; pl < 128; ++pl) {
        if (idx_s[pl] == k) {
          const float4* row = (const float4*)(&Xs[(pl - 64) * XPITCH + dg * 64]);
#pragma unroll
          for (int q = 0; q < 16; ++q) {
            const float4 x = row[q];
            s[q].x += x.x; s[q].y += x.y; s[q].z += x.z; s[q].w += x.w;
          }
          cnt++;
        }
      }
      float4* out = (float4*)(&g_part[c][k][dg * 64]);
#pragma unroll
      for (int q = 0; q < 16; ++q) out[q] = s[q];
      if (dg == 0) g_pcnt[c][k] = cnt;
    }
    grid_barrier(c, base + (++bar));  // A: g_part/g_pcnt published + L2 inv'd

    // ---- upB for cluster c (exact round-4 chain; oldc carried in register) --
    {
      float s = 0.f;
#pragma unroll 4
      for (int ch = 0; ch < NCHUNK; ++ch) s += g_part[ch][c][t];
      int cnt = 0;
#pragma unroll 4
      for (int ch = 0; ch < NCHUNK; ++ch) cnt += g_pcnt[ch][c];
      const float nc = (cnt > 0) ? (s / (float)cnt) : myc;
      myc = nc;
      g_centT[t * KC + c] = nc;
      red[t] = nc * nc;
      __syncthreads();
      for (int o = 128; o > 0; o >>= 1) {
        if (t < o) red[t] += red[t + o];
        __syncthreads();
      }
      if (t == 0) g_csq[c] = red[0];
    }
    grid_barrier(c, base + (++bar));  // B: new centroids visible
  }
}

// mask write: out[b,h,i,j] = (cid[b,i]==cid[b,j]) ? 0 : -10000. 16 rows/block.
__global__ void __launch_bounds__(256) k_mask(float* __restrict__ out, int H) {
  const int blk = blockIdx.x;
  const int tiles = LSEQ / 16;  // 256
  const int b = blk / (H * tiles);
  const int h = (blk / tiles) % H;
  const int tile = blk % tiles;
  const int t = threadIdx.x;
  __shared__ int cid[LSEQ];  // 16 KB
  for (int j = t; j < LSEQ; j += 256) cid[j] = g_idx[b * LSEQ + j];
  __syncthreads();
  const size_t base = ((size_t)(b * H + h) * LSEQ + (size_t)tile * 16) * LSEQ;
  for (int r = 0; r < 16; ++r) {
    const int my = cid[tile * 16 + r];
    float4* orow = (float4*)(out + base + (size_t)r * LSEQ);
#pragma unroll
    for (int s = 0; s < 4; ++s) {
      const int c4 = s * 256 + t;  // float4 index within row
      const int j = c4 * 4;
      float4 v;
      v.x = (cid[j + 0] == my) ? 0.f : -10000.f;
      v.y = (cid[j + 1] == my) ? 0.f : -10000.f;
      v.z = (cid[j + 2] == my) ? 0.f : -10000.f;
      v.w = (cid[j + 3] == my) ? 0.f : -10000.f;
      orow[c4] = v;
    }
  }
}

// ---------------- launch -----------------------------------------------------
extern "C" void kernel_launch(void* const* d_in, const int* in_sizes, int n_in,
                              void* d_out, int out_size, void* d_ws, size_t ws_size,
                              hipStream_t stream) {
  const float* qk = (const float*)d_in[0];
  const float* W = (const float*)d_in[1];
  const int H = out_size / (NB * LSEQ * LSEQ);  // 8

  const InitIdx ii = compute_init_indices();  // pure host integer math

  k_R_xsq<<<NB * (LSEQ / 8), 256, 0, stream>>>(qk, W);
  k_kmeans<<<NBLK, 256, 0, stream>>>(ii);
  k_mask<<<NB * H * (LSEQ / 16), 256, 0, stream>>>((float*)d_out, H);
}